// Round 7
// baseline (172.487 us; speedup 1.0000x reference)
//
#include <hip/hip_runtime.h>

typedef unsigned short u16;
typedef unsigned int u32;
typedef short bf16x8 __attribute__((ext_vector_type(8)));
typedef float f32x4 __attribute__((ext_vector_type(4)));

#define HH 128

__device__ __forceinline__ u16 f2bf(float f) {
  u32 u = __float_as_uint(f);
  u += 0x7fffu + ((u >> 16) & 1u);  // round-to-nearest-even
  return (u16)(u >> 16);
}
__device__ __forceinline__ u32 pack2(float a, float b) {
  return (u32)f2bf(a) | ((u32)f2bf(b) << 16);
}
__device__ __forceinline__ float bf2f(u16 h) {
  return __uint_as_float(((u32)h) << 16);
}

__device__ __forceinline__ void lds_dma16(const void* g, void* l) {
  __builtin_amdgcn_global_load_lds(
      (const __attribute__((address_space(1))) u32*)g,
      (__attribute__((address_space(3))) u32*)l, 16, 0, 0);
}

// ws element map (u16 units): [0, 1048576) W_comb; then Ab regions:
//   cnn 8388608 @ +0, gaz 2097152 @ +8388608, gazb @ +10485760,
//   gm @ +12582912, exper @ +14680064  (Ab base = ws + 1048576)
#define AB_CNN 0
#define AB_GAZ 8388608
#define AB_GAZB 10485760
#define AB_GM 12582912
#define AB_EXP 14680064

// ---------------------------------------------------------------------------
// Pre-pass 1: fused W_comb (bf16), chunk-transposed + bank-swizzled.
// Chunk index (((q*16+kc)*512+n)*4+p) holds W[k = kc*32 + lq*8 + j][col n],
// lq = p ^ (n&3) ^ ((n>>2)&3).
// ---------------------------------------------------------------------------
__global__ __launch_bounds__(256) void prep_w(const float* __restrict__ Wcat,
                                              const float* __restrict__ Wexp,
                                              u16* __restrict__ Wc) {
  const int bx = blockIdx.x;      // 512 blocks: ((q*16+kc)*8 + nt)
  const int nt = bx & 7;
  const int kc = (bx >> 3) & 15;
  const int q = bx >> 7;
  __shared__ u16 T[32 * 72];

  const int tid = threadIdx.x;
  const int r = tid >> 3;
  const int c8 = (tid & 7) * 8;
  float v[8];
  if (kc < 12) {
    const float* src =
        Wcat + (size_t)(kc * 32 + r) * 2048 + q * 512 + nt * 64 + c8;
    float4 a = *(const float4*)src;
    float4 b = *(const float4*)(src + 4);
    v[0] = a.x; v[1] = a.y; v[2] = a.z; v[3] = a.w;
    v[4] = b.x; v[5] = b.y; v[6] = b.z; v[7] = b.w;
  } else if (nt >= 2) {
    const float* src = Wexp + (size_t)((kc - 12) * 32 + r) * 1536 + q * 384 +
                       nt * 64 + c8 - 128;
    float4 a = *(const float4*)src;
    float4 b = *(const float4*)(src + 4);
    v[0] = a.x; v[1] = a.y; v[2] = a.z; v[3] = a.w;
    v[4] = b.x; v[5] = b.y; v[6] = b.z; v[7] = b.w;
  } else {
#pragma unroll
    for (int j = 0; j < 8; ++j) v[j] = 0.f;
  }
  uint4 pk;
  pk.x = pack2(v[0], v[1]);
  pk.y = pack2(v[2], v[3]);
  pk.z = pack2(v[4], v[5]);
  pk.w = pack2(v[6], v[7]);
  *(uint4*)&T[r * 72 + c8] = pk;
  __syncthreads();

  const int p = tid & 3;
  const int nl = tid >> 2;
  const int lq = p ^ (nl & 3) ^ ((nl >> 2) & 3);
  u16 w[8];
#pragma unroll
  for (int j = 0; j < 8; ++j) w[j] = T[(lq * 8 + j) * 72 + nl];
  uint4 o;
  o.x = (u32)w[0] | ((u32)w[1] << 16);
  o.y = (u32)w[2] | ((u32)w[3] << 16);
  o.z = (u32)w[4] | ((u32)w[5] << 16);
  o.w = (u32)w[6] | ((u32)w[7] << 16);
  const size_t idx = ((size_t)((q * 16 + kc) * 512) + nt * 64 + nl) * 4 + p;
  ((uint4*)Wc)[idx] = o;
}

// ---------------------------------------------------------------------------
// Pre-pass 2: stream-convert the 5 fp32 activation inputs to bf16 (natural
// layout) so the GEMM kernel can stage A with pure global_load_lds DMA.
// 16.78M elems; thread handles 32 elems (2 float4-pairs -> 2 uint4 stores).
// ---------------------------------------------------------------------------
__global__ __launch_bounds__(256) void prep_a(
    const float* __restrict__ CNN, const float* __restrict__ gaz,
    const float* __restrict__ gazb, const float* __restrict__ gm,
    const float* __restrict__ exper, u16* __restrict__ Ab) {
  const int gid = blockIdx.x * 256 + threadIdx.x;  // 0..524287
  const int i0 = gid * 32;
  const float* src;
  int off;
  if (i0 < AB_GAZ) {
    src = CNN; off = i0 - AB_CNN;
  } else if (i0 < AB_GAZB) {
    src = gaz; off = i0 - AB_GAZ;
  } else if (i0 < AB_GM) {
    src = gazb; off = i0 - AB_GAZB;
  } else if (i0 < AB_EXP) {
    src = gm; off = i0 - AB_GM;
  } else {
    src = exper; off = i0 - AB_EXP;
  }
#pragma unroll
  for (int j = 0; j < 4; ++j) {
    float4 a = *(const float4*)(src + off + j * 8);
    float4 b = *(const float4*)(src + off + j * 8 + 4);
    uint4 pk;
    pk.x = pack2(a.x, a.y);
    pk.y = pack2(a.z, a.w);
    pk.z = pack2(b.x, b.y);
    pk.w = pack2(b.z, b.w);
    *(uint4*)(Ab + i0 + j * 8) = pk;
  }
}

// ---------------------------------------------------------------------------
// Fused GEMM + gate epilogue — DMA-staged A, 2-deep B prefetch.
// Block: (b,q) x 64-row tile x full 128-h slab, 8 waves (wave w owns columns
// {gg*128 + w*16 + c}, gg 0..3: softmax-coupled, register-local).
// A (64x512 bf16, 64 KB LDS) staged via 8 global_load_lds width=16 per thread
// (zero VGPR, zero VALU; XOR swizzle realized on the per-lane GLOBAL address;
// LDS side is the mandated uniform-base + lane*16). ONE barrier total.
// B streamed global->VGPR (W_comb L2-resident); MFMA ordered gg-major and
// each bcur[gg] reloaded for kc+2 right after its 4 MFMAs -> ~1.75-body
// prefetch distance with only 2x4 B-registers.
// Epilogue reads CNN (kc 0..3) / exper (kc 12..15) back out of Abuf.
// 2 blocks/CU (128 KB LDS); launch_bounds(512,4): combined regs <= 128.
// ---------------------------------------------------------------------------
__global__ __launch_bounds__(512, 4) void fused_gate(
    const u16* __restrict__ Wc, const u16* __restrict__ Ab,
    const float* __restrict__ bcat, const float* __restrict__ bexp,
    float* __restrict__ out) {
  __shared__ u16 Abuf[16 * 64 * 32];  // 64 KB

  const int tid = threadIdx.x;
  const int lane = tid & 63;
  const int wave = tid >> 6;  // 0..7
  const int bx = blockIdx.x;  // 1024: grp*8 + tile
  const int tile = bx & 7;
  const int grp = bx >> 3;
  const int b = grp >> 2;
  const int q = grp & 3;
  const int s_base = tile * 64;

  // ---- stage A via DMA: wave w handles kc slots {w, 8+w}, 4 instrs each ----
  const int cnn_b = AB_CNN + (b * 2048 + q * 512 + s_base) * HH;
  const int gaz_b = AB_GAZ + (q & 1) * 2097152 + (b * 512 + s_base) * HH;
  const int gm_b = AB_GM + (b * 512 + s_base) * HH;
  const int exp_b = AB_EXP + (b * 512 + s_base) * HH;
  const int rloc = lane >> 2;   // row within 16-row group
  const int oph = lane & 3;     // physical octet (LDS side fixed by lane)
#pragma unroll
  for (int jj = 0; jj < 2; ++jj) {
    const int j = wave + jj * 8;  // kc slot, wave-uniform
    const int sel = j >> 2;
    const int sb = (sel == 0) ? cnn_b
                 : (sel == 1) ? gaz_b
                 : (sel == 2) ? gm_b
                              : exp_b;
#pragma unroll
    for (int t = 0; t < 4; ++t) {
      const int row = t * 16 + rloc;
      const int o = oph ^ ((row & 3) ^ ((row >> 2) & 3)) ^ sel;  // inv swizzle
      lds_dma16(Ab + sb + row * HH + (j & 3) * 32 + o * 8,
                &Abuf[(j * 64 + t * 16) * 32]);
    }
  }

  // ---- B setup: load kc0 + kc1 fragments (drained by the barrier) ----
  const int l15 = lane & 15;
  const int quad = lane >> 4;
  const int sl = (l15 & 3) ^ ((l15 >> 2) & 3);
  const int physB = quad ^ sl;
  const u16* wq = Wc + q * 262144;  // q slab (uniform)
  int nofs[4];
#pragma unroll
  for (int gg = 0; gg < 4; ++gg)
    nofs[gg] = ((gg * 128 + wave * 16 + l15) * 4 + physB) * 8;

  bf16x8 b0[4], b1[4];
#pragma unroll
  for (int gg = 0; gg < 4; ++gg) b0[gg] = *(const bf16x8*)(wq + nofs[gg]);
#pragma unroll
  for (int gg = 0; gg < 4; ++gg)
    b1[gg] = *(const bf16x8*)(wq + 16384 + nofs[gg]);

  f32x4 acc[4][4];
#pragma unroll
  for (int rt = 0; rt < 4; ++rt)
#pragma unroll
    for (int gg = 0; gg < 4; ++gg) acc[rt][gg] = (f32x4)0.f;

  __syncthreads();  // drains DMA + B loads

  // ---- K-loop: gg-major MFMA, reload consumed slot for kc+2 ----
#pragma unroll
  for (int kc = 0; kc < 16; ++kc) {
    const int pa = (quad ^ sl ^ (kc >> 2)) * 8;
    bf16x8 af[4];
#pragma unroll
    for (int rt = 0; rt < 4; ++rt)
      af[rt] = *(const bf16x8*)&Abuf[(kc * 64 + rt * 16 + l15) * 32 + pa];
#pragma unroll
    for (int gg = 0; gg < 4; ++gg) {
      bf16x8* bc = (kc & 1) ? b1 : b0;
#pragma unroll
      for (int rt = 0; rt < 4; ++rt)
        acc[rt][gg] = __builtin_amdgcn_mfma_f32_16x16x32_bf16(
            af[rt], bc[gg], acc[rt][gg], 0, 0, 0);
      if (kc < 14)
        bc[gg] = *(const bf16x8*)(wq + (kc + 2) * 16384 + nofs[gg]);
    }
  }

  // ---- epilogue: tanh / sigmoid / softmax-of-3 / weighted state sum ----
  const float* bcq = bcat + q * 512;
  const float* beq = bexp + q * 384;
  const int outbase = ((q * 32 + b) * 512 + s_base) * HH;
  const int h = wave * 16 + l15;  // 0..127
  const float bc0 = bcq[h];
  const float bc1 = bcq[128 + h];
  const float bc2 = bcq[256 + h];
  const float bc3 = bcq[384 + h];
  const float be1 = beq[h];
  const float be2 = beq[128 + h];
  const float be3 = beq[256 + h];
  const int kcc = h >> 5;         // CNN chunk (0..3)
  const int kce = 12 + (h >> 5);  // exper chunk (12..15)
  const int oh = (h >> 3) & 3;
  const int he = h & 7;
#pragma unroll
  for (int rt = 0; rt < 4; ++rt) {
#pragma unroll
    for (int r = 0; r < 4; ++r) {
      const int row = rt * 16 + quad * 4 + r;
      const int srw = r ^ quad;  // == (row&3)^((row>>2)&3)
      const float cnn = bf2f(Abuf[(kcc * 64 + row) * 32 + (oh ^ srw) * 8 + he]);
      const float ex =
          bf2f(Abuf[(kce * 64 + row) * 32 + (oh ^ srw ^ 3) * 8 + he]);
      const float c0 = acc[rt][0][r] + bc0;
      const float p1 = acc[rt][1][r] + bc1 + be1;
      const float p2 = acc[rt][2][r] + bc2 + be2;
      const float p3 = acc[rt][3][r] + bc3 + be3;
      const float e2c = __expf(2.f * c0);
      const float ns = 1.f - 2.f * __builtin_amdgcn_rcpf(e2c + 1.f);  // tanh
      const float g1 = __builtin_amdgcn_rcpf(1.f + __expf(-p1));
      const float g2 = __builtin_amdgcn_rcpf(1.f + __expf(-p2));
      const float g3 = __builtin_amdgcn_rcpf(1.f + __expf(-p3));
      const float e1 = __expf(g1);
      const float e2 = __expf(g2);
      const float e3 = __expf(g3);
      const float inv = __builtin_amdgcn_rcpf(e1 + e2 + e3);
      out[outbase + row * HH + h] = (e1 * ns + e2 * cnn + e3 * ex) * inv;
    }
  }
}

extern "C" void kernel_launch(void* const* d_in, const int* in_sizes, int n_in,
                              void* d_out, int out_size, void* d_ws, size_t ws_size,
                              hipStream_t stream) {
  const float* CNN = (const float*)d_in[0];
  const float* gaz = (const float*)d_in[1];
  const float* gazb = (const float*)d_in[2];
  const float* gm = (const float*)d_in[3];
  const float* exper = (const float*)d_in[4];
  const float* Wcat = (const float*)d_in[5];
  const float* bcat = (const float*)d_in[6];
  const float* Wexp = (const float*)d_in[7];
  const float* bexp = (const float*)d_in[8];
  u16* Wc = (u16*)d_ws;            // 2 MB fused bf16 weights
  u16* Ab = Wc + 1048576;          // 33.5 MB bf16 activations

  prep_w<<<512, 256, 0, stream>>>(Wcat, Wexp, Wc);
  prep_a<<<2048, 256, 0, stream>>>(CNN, gaz, gazb, gm, exper, Ab);
  fused_gate<<<1024, 512, 0, stream>>>(Wc, Ab, bcat, bexp, (float*)d_out);
}